// Round 1
// baseline (996.935 us; speedup 1.0000x reference)
//
#include <hip/hip_runtime.h>
#include <hip/hip_bf16.h>
#include <stdint.h>

// HadLinear: out[b,s,o] = sum_i blockFWHT1024(x)[b,s,i]/32 * W[o,i]
// Equivalently (H symmetric, linear): out = x @ Wh^T with Wh = blockFWHT1024(W rows)/32.
// Pipeline: (1) x f32->bf16, (2) Wh = FWHT(W)/32 -> bf16, (3) bf16 MFMA GEMM (m97 128^2 structure).
//
// Workspace layout (needs 160 MiB):
//   [0, 128 MiB)  : x_bf16   (16384 x 4096 u16)
//   [128, 160 MiB): Wh_bf16  ( 4096 x 4096 u16)

typedef __attribute__((ext_vector_type(8))) short    short8;   // 8 bf16 (4 VGPRs), MFMA A/B frag
typedef __attribute__((ext_vector_type(4))) float    f32x4;    // MFMA C/D frag
typedef __attribute__((ext_vector_type(8))) uint16_t u16x8;

static constexpr int MDIM = 16384;   // B*S = 4*4096
static constexpr int NDIM = 4096;    // D_out
static constexpr int KDIM = 4096;    // D_in
static constexpr int BM = 128, BN = 128, BK = 32;

__device__ __forceinline__ uint16_t f2bf(float f) {
  // round-to-nearest-even f32 -> bf16 (inputs finite; no NaN handling needed)
  union { float f; uint32_t u; } c; c.f = f;
  uint32_t u = c.u;
  return (uint16_t)((u + 0x7FFFu + ((u >> 16) & 1u)) >> 16);
}

// ---------------- kernel 1: x (f32) -> bf16 ----------------
__global__ __launch_bounds__(256) void cvt_x_kernel(const float* __restrict__ x,
                                                    uint16_t* __restrict__ xb, int n8) {
  int stride = gridDim.x * blockDim.x;
  for (int t = blockIdx.x * blockDim.x + threadIdx.x; t < n8; t += stride) {
    const float4* p = reinterpret_cast<const float4*>(x + (size_t)t * 8);
    float4 a = p[0], b = p[1];
    u16x8 o;
    o[0] = f2bf(a.x); o[1] = f2bf(a.y); o[2] = f2bf(a.z); o[3] = f2bf(a.w);
    o[4] = f2bf(b.x); o[5] = f2bf(b.y); o[6] = f2bf(b.z); o[7] = f2bf(b.w);
    *reinterpret_cast<u16x8*>(xb + (size_t)t * 8) = o;
  }
}

// ---------------- kernel 2: Wh = blockFWHT1024(W)/32 -> bf16 ----------------
// grid = 4096 rows * 4 blocks-of-1024 = 16384; one 1024-chunk per block.
__global__ __launch_bounds__(256) void fwht_w_kernel(const float* __restrict__ W,
                                                     uint16_t* __restrict__ Wh) {
  __shared__ float s[1024];
  const int tid = threadIdx.x;
  const size_t base = (size_t)blockIdx.x * 1024;   // chunks are contiguous in memory

  // load 1024 floats (float4 per thread)
  reinterpret_cast<float4*>(s)[tid] = reinterpret_cast<const float4*>(W + base)[tid];
  __syncthreads();

  for (int h = 1; h < 1024; h <<= 1) {
    #pragma unroll
    for (int pp = 0; pp < 2; ++pp) {
      int p = tid + pp * 256;          // 512 butterflies per stage
      int q = p & (h - 1);
      int i = ((p - q) << 1) | q;
      float a = s[i], b = s[i + h];
      s[i] = a + b;
      s[i + h] = a - b;
    }
    __syncthreads();
  }

  #pragma unroll
  for (int pp = 0; pp < 4; ++pp) {
    int i = tid + pp * 256;
    Wh[base + i] = f2bf(s[i] * 0.03125f);   // 1/sqrt(1024)
  }
}

// ---------------- kernel 3: C[M,N] = A[M,K] * B[N,K]^T (bf16 in, f32 out) ----------------
// m97 structure: 128x128 tile, BK=32, 256 threads (4 waves, 2x2), each wave 64x64
// via 4x4 grid of 16x16x32 MFMA fragments; global_load_lds width=16 staging.
__global__ __launch_bounds__(256) void gemm_bt(const uint16_t* __restrict__ A,
                                               const uint16_t* __restrict__ B,
                                               float* __restrict__ C) {
  __shared__ __align__(16) uint16_t Alds[BM * BK];   // 8 KiB, linear [128][32]
  __shared__ __align__(16) uint16_t Blds[BN * BK];   // 8 KiB

  const int tid  = threadIdx.x;
  const int wave = tid >> 6;
  const int lane = tid & 63;

  const int nTilesN = NDIM / BN;                 // 32
  const int tile_m  = blockIdx.x / nTilesN;
  const int tile_n  = blockIdx.x % nTilesN;

  const int wm = (wave >> 1) * 64;               // wave row offset in tile
  const int wn = (wave & 1) * 64;                // wave col offset in tile

  f32x4 acc[4][4] = {};

  // staging: per issue i (0,1), wave w stages chunk = i*4+w (16 rows x 32 k = 1 KiB)
  // LDS dest is wave-uniform base; HW scatters lane*16B. Global src is per-lane:
  //   row = chunk*16 + lane/4, col = (lane&3)*8   (4 lanes = 64 contiguous bytes)
  const int srow = lane >> 2;
  const int scol = (lane & 3) * 8;
  const uint16_t* agp[2];
  const uint16_t* bgp[2];
  uint16_t* alp[2];
  uint16_t* blp[2];
  #pragma unroll
  for (int i = 0; i < 2; ++i) {
    int chunk = i * 4 + wave;
    int row = chunk * 16 + srow;
    agp[i] = A + (size_t)(tile_m * BM + row) * KDIM + scol;
    bgp[i] = B + (size_t)(tile_n * BN + row) * KDIM + scol;
    alp[i] = &Alds[chunk * 512];
    blp[i] = &Blds[chunk * 512];
  }

  for (int k0 = 0; k0 < KDIM; k0 += BK) {
    #pragma unroll
    for (int i = 0; i < 2; ++i) {
      __builtin_amdgcn_global_load_lds(
          (const __attribute__((address_space(1))) unsigned int*)(agp[i] + k0),
          (__attribute__((address_space(3))) unsigned int*)(alp[i]), 16, 0, 0);
      __builtin_amdgcn_global_load_lds(
          (const __attribute__((address_space(1))) unsigned int*)(bgp[i] + k0),
          (__attribute__((address_space(3))) unsigned int*)(blp[i]), 16, 0, 0);
    }
    __syncthreads();   // compiler emits vmcnt(0) drain before s_barrier

    // A/B fragment loads: lane reads 8 contiguous k at row (lane&15), k0=(lane>>4)*8
    short8 af[4], bf[4];
    #pragma unroll
    for (int mi = 0; mi < 4; ++mi)
      af[mi] = *reinterpret_cast<const short8*>(
          &Alds[(wm + mi * 16 + (lane & 15)) * BK + (lane >> 4) * 8]);
    #pragma unroll
    for (int ni = 0; ni < 4; ++ni)
      bf[ni] = *reinterpret_cast<const short8*>(
          &Blds[(wn + ni * 16 + (lane & 15)) * BK + (lane >> 4) * 8]);

    #pragma unroll
    for (int mi = 0; mi < 4; ++mi)
      #pragma unroll
      for (int ni = 0; ni < 4; ++ni)
        acc[mi][ni] = __builtin_amdgcn_mfma_f32_16x16x32_bf16(af[mi], bf[ni],
                                                              acc[mi][ni], 0, 0, 0);
    __syncthreads();   // protect LDS before next stage
  }

  // epilogue: C/D layout (m89/m91-verified): col = lane&15, row = (lane>>4)*4 + j
  float* Cp = C + (size_t)(tile_m * BM) * NDIM + tile_n * BN;
  const int cr = (lane >> 4) * 4;
  const int cc = lane & 15;
  #pragma unroll
  for (int mi = 0; mi < 4; ++mi)
    #pragma unroll
    for (int ni = 0; ni < 4; ++ni)
      #pragma unroll
      for (int j = 0; j < 4; ++j)
        Cp[(size_t)(wm + mi * 16 + cr + j) * NDIM + (wn + ni * 16 + cc)] = acc[mi][ni][j];
}

extern "C" void kernel_launch(void* const* d_in, const int* in_sizes, int n_in,
                              void* d_out, int out_size, void* d_ws, size_t ws_size,
                              hipStream_t stream) {
  (void)in_sizes; (void)n_in; (void)out_size; (void)ws_size;
  const float* x = (const float*)d_in[0];   // (4,4096,4096) f32
  const float* w = (const float*)d_in[1];   // (4096,4096) f32
  float* out = (float*)d_out;               // (4,4096,4096) f32

  uint16_t* xb = (uint16_t*)d_ws;                       // 16384*4096 bf16 = 128 MiB
  uint16_t* wh = xb + (size_t)MDIM * KDIM;              // 4096*4096 bf16 = 32 MiB

  // (1) x -> bf16  (67.1M elems, 8/thread)
  cvt_x_kernel<<<2048, 256, 0, stream>>>(x, xb, (MDIM * (size_t)KDIM) / 8);
  // (2) Wh = blockFWHT(W)/32 -> bf16
  fwht_w_kernel<<<(NDIM * KDIM) / 1024, 256, 0, stream>>>(w, wh);
  // (3) GEMM: out = xb * wh^T
  gemm_bt<<<(MDIM / BM) * (NDIM / BN), 256, 0, stream>>>(xb, wh, out);
}

// Round 2
// 808.606 us; speedup vs baseline: 1.2329x; 1.2329x over previous
//
#include <hip/hip_runtime.h>
#include <hip/hip_bf16.h>
#include <stdint.h>

// HadLinear: out = blockFWHT1024(x)/32 @ W^T  ==  x @ (blockFWHT1024(W rows)/32)^T
// Pipeline: (1) x f32->bf16, (2) Wh = FWHT(W)/32 -> bf16, (3) bf16 MFMA GEMM.
// GEMM: 256x256 tile, BK=32, 8 waves (2Mx4N), 4-slot LDS ring, 3-tile-deep
// counted-vmcnt pipeline (T3/T4), LDS XOR swizzle (T2, both-sides), raw
// s_barrier (no vmcnt(0) drain), setprio around MFMA (T5), XCD swizzle (T1).

typedef __attribute__((ext_vector_type(8))) short    short8;   // 8 bf16
typedef __attribute__((ext_vector_type(4))) float    f32x4;
typedef __attribute__((ext_vector_type(8))) uint16_t u16x8;

static constexpr int MDIM = 16384;   // B*S
static constexpr int NDIM = 4096;    // D_out
static constexpr int KDIM = 4096;    // D_in
static constexpr int BM = 256, BN = 256, BK = 32;
static constexpr int NT = KDIM / BK;           // 128 K-tiles

__device__ __forceinline__ uint16_t f2bf(float f) {
  union { float f; uint32_t u; } c; c.f = f;
  uint32_t u = c.u;
  return (uint16_t)((u + 0x7FFFu + ((u >> 16) & 1u)) >> 16);
}

// ---------------- kernel 1: x (f32) -> bf16 ----------------
__global__ __launch_bounds__(256) void cvt_x_kernel(const float* __restrict__ x,
                                                    uint16_t* __restrict__ xb, int n8) {
  int stride = gridDim.x * blockDim.x;
  for (int t = blockIdx.x * blockDim.x + threadIdx.x; t < n8; t += stride) {
    const float4* p = reinterpret_cast<const float4*>(x + (size_t)t * 8);
    float4 a = p[0], b = p[1];
    u16x8 o;
    o[0] = f2bf(a.x); o[1] = f2bf(a.y); o[2] = f2bf(a.z); o[3] = f2bf(a.w);
    o[4] = f2bf(b.x); o[5] = f2bf(b.y); o[6] = f2bf(b.z); o[7] = f2bf(b.w);
    *reinterpret_cast<u16x8*>(xb + (size_t)t * 8) = o;
  }
}

// ---------------- kernel 2: Wh = blockFWHT1024(W)/32 -> bf16 ----------------
__global__ __launch_bounds__(256) void fwht_w_kernel(const float* __restrict__ W,
                                                     uint16_t* __restrict__ Wh) {
  __shared__ float s[1024];
  const int tid = threadIdx.x;
  const size_t base = (size_t)blockIdx.x * 1024;

  reinterpret_cast<float4*>(s)[tid] = reinterpret_cast<const float4*>(W + base)[tid];
  __syncthreads();

  for (int h = 1; h < 1024; h <<= 1) {
    #pragma unroll
    for (int pp = 0; pp < 2; ++pp) {
      int p = tid + pp * 256;
      int q = p & (h - 1);
      int i = ((p - q) << 1) | q;
      float a = s[i], b = s[i + h];
      s[i] = a + b;
      s[i + h] = a - b;
    }
    __syncthreads();
  }

  #pragma unroll
  for (int pp = 0; pp < 4; ++pp) {
    int i = tid + pp * 256;
    Wh[base + i] = f2bf(s[i] * 0.03125f);
  }
}

// ---------------- kernel 3: deep-pipelined 256^2 GEMM, C = A * B^T ----------------
// LDS image of a K-tile slot: 256 rows x 4 chunks of 16B. Chunk stored at
// (r, c') holds global chunk (r, c) with c = c' ^ ((r>>1)&3)  (involution).
// global_load_lds writes linearly (chunk index n = j*512 + wave*64 + lane),
// so the SOURCE address applies the inverse swizzle; ds_read applies it again.

#define KBODY(VM)                                                              \
  do {                                                                         \
    asm volatile("s_waitcnt vmcnt(" #VM ")" ::: "memory");                     \
    __builtin_amdgcn_s_barrier();                                              \
    asm volatile("" ::: "memory");                                             \
    __builtin_amdgcn_sched_barrier(0);                                         \
    const int slot_ = kt & 3;                                                  \
    const char* ra_ = aRd + slot_ * 16384;                                     \
    const char* rb_ = bRd + slot_ * 16384;                                     \
    short8 af[8], bf[4];                                                       \
    _Pragma("unroll")                                                          \
    for (int m = 0; m < 8; ++m) af[m] = *(const short8*)(ra_ + m * 1024);      \
    _Pragma("unroll")                                                          \
    for (int n = 0; n < 4; ++n) bf[n] = *(const short8*)(rb_ + n * 1024);      \
    __builtin_amdgcn_s_setprio(1);                                             \
    _Pragma("unroll")                                                          \
    for (int m = 0; m < 8; ++m)                                                \
      _Pragma("unroll")                                                        \
      for (int n = 0; n < 4; ++n)                                              \
        acc[m][n] = __builtin_amdgcn_mfma_f32_16x16x32_bf16(af[m], bf[n],      \
                                                            acc[m][n], 0, 0, 0); \
    __builtin_amdgcn_s_setprio(0);                                             \
    asm volatile("" ::: "memory");                                             \
    __builtin_amdgcn_s_barrier();                                              \
    __builtin_amdgcn_sched_barrier(0);                                         \
  } while (0)

__global__ __launch_bounds__(512, 2) void gemm_bt(const uint16_t* __restrict__ A,
                                                  const uint16_t* __restrict__ B,
                                                  float* __restrict__ C) {
  __shared__ __align__(16) uint16_t Ab[4][BM * BK];   // 4 x 16 KiB
  __shared__ __align__(16) uint16_t Bb[4][BN * BK];   // 4 x 16 KiB  (128 KiB total)

  const int tid = threadIdx.x;
  const int wv  = tid >> 6;
  const int l   = tid & 63;

  // XCD-bijective swizzle: 1024 wgs, 8 XCDs, 128 per XCD (nwg % 8 == 0).
  const int wg = ((blockIdx.x & 7) << 7) | (blockIdx.x >> 3);
  const int tm = wg >> 4;          // 64 M-tiles
  const int tn = wg & 15;          // 16 N-tiles
  const int wm = wv >> 2;          // wave rows: wm*128
  const int wn = wv & 3;           // wave cols: wn*64

  // ---- staging source addresses (inverse-swizzled global) ----
  // chunk n = j*512 + wv*64 + l  ->  r = j*128 + wv*16 + (l>>2), c' = l&3
  // source chunk col c = c' ^ ((r>>1)&3) = (l&3) ^ ((l>>3)&3)   (lane-constant)
  const int sr = l >> 2;
  const int sc = (l & 3) ^ ((l >> 3) & 3);
  const uint16_t* a_src[2];
  const uint16_t* b_src[2];
  #pragma unroll
  for (int j = 0; j < 2; ++j) {
    a_src[j] = A + (size_t)(tm * BM + j * 128 + wv * 16 + sr) * KDIM + sc * 8;
    b_src[j] = B + (size_t)(tn * BN + j * 128 + wv * 16 + sr) * KDIM + sc * 8;
  }

  // ---- swizzled ds_read base (read-side XOR, lane-constant) ----
  // frag row = {wm*128|wn*64} + m*16 + (l&15); byte col = ((l>>4) ^ (((l&15)>>1)&3))*16
  const int lA = l & 15;
  const int rc = ((l >> 4) ^ ((lA >> 1) & 3)) * 16;
  const char* aRd = (const char*)&Ab[0][0] + (wm * 128 + lA) * 64 + rc;
  const char* bRd = (const char*)&Bb[0][0] + (wn * 64 + lA) * 64 + rc;

  f32x4 acc[8][4] = {};

  auto STAGE = [&](int t) {
    const int slot = t & 3;
    #pragma unroll
    for (int j = 0; j < 2; ++j) {
      __builtin_amdgcn_global_load_lds(
          (const __attribute__((address_space(1))) unsigned int*)(a_src[j] + (size_t)t * BK),
          (__attribute__((address_space(3))) unsigned int*)((char*)&Ab[slot][0] + j * 8192 + wv * 1024),
          16, 0, 0);
      __builtin_amdgcn_global_load_lds(
          (const __attribute__((address_space(1))) unsigned int*)(b_src[j] + (size_t)t * BK),
          (__attribute__((address_space(3))) unsigned int*)((char*)&Bb[slot][0] + j * 8192 + wv * 1024),
          16, 0, 0);
    }
  };

  // prologue: 3 tiles in flight (12 loads/wave)
  STAGE(0); STAGE(1); STAGE(2);

  int kt = 0;
  for (; kt < NT - 3; ++kt) {      // kt = 0..124, stages tiles 3..127
    STAGE(kt + 3);                 // 16 outstanding -> wait to 12: tile kt landed
    KBODY(12);
  }
  KBODY(8);  ++kt;                 // tile 125 landed (126,127 in flight)
  KBODY(4);  ++kt;                 // tile 126 landed
  KBODY(0);                        // tile 127 landed

  // ---- epilogue: C/D layout col = lane&15, row = (lane>>4)*4 + j ----
  float* Cp = C + (size_t)(tm * BM + wm * 128) * NDIM + tn * BN + wn * 64;
  const int co = (l >> 4) * 4;
  const int cc = l & 15;
  #pragma unroll
  for (int m = 0; m < 8; ++m)
    #pragma unroll
    for (int n = 0; n < 4; ++n)
      #pragma unroll
      for (int j = 0; j < 4; ++j)
        Cp[(size_t)(m * 16 + co + j) * NDIM + n * 16 + cc] = acc[m][n][j];
}

extern "C" void kernel_launch(void* const* d_in, const int* in_sizes, int n_in,
                              void* d_out, int out_size, void* d_ws, size_t ws_size,
                              hipStream_t stream) {
  (void)in_sizes; (void)n_in; (void)out_size; (void)ws_size;
  const float* x = (const float*)d_in[0];   // (4,4096,4096) f32
  const float* w = (const float*)d_in[1];   // (4096,4096) f32
  float* out = (float*)d_out;               // (4,4096,4096) f32

  uint16_t* xb = (uint16_t*)d_ws;                       // 128 MiB
  uint16_t* wh = xb + (size_t)MDIM * KDIM;              // 32 MiB

  cvt_x_kernel<<<2048, 256, 0, stream>>>(x, xb, (int)((MDIM * (size_t)KDIM) / 8));
  fwht_w_kernel<<<(NDIM * KDIM) / 1024, 256, 0, stream>>>(w, wh);
  gemm_bt<<<(MDIM / BM) * (NDIM / BN), 512, 0, stream>>>(xb, wh, out);
}

// Round 3
// 694.098 us; speedup vs baseline: 1.4363x; 1.1650x over previous
//
#include <hip/hip_runtime.h>
#include <hip/hip_bf16.h>
#include <stdint.h>

// HadLinear: out = blockFWHT1024(x)/32 @ W^T  ==  x @ (blockFWHT1024(W rows)/32)^T
// (1) x f32->bf16, (2) Wh = FWHT(W)/32 -> bf16, (3) bf16 MFMA GEMM.
// GEMM: m201-style 8-phase schedule. BM=BN=256, BK=64, 8 waves (2Mx4N),
// 2-buffer LDS (128 KiB), 1 half-tile staged per phase, counted vmcnt(2) at
// phases 4/8 (2-phase lead), XOR chunk swizzle (both-sides), setprio on MFMA.

typedef __attribute__((ext_vector_type(8))) short    short8;
typedef __attribute__((ext_vector_type(4))) float    f32x4;
typedef __attribute__((ext_vector_type(8))) uint16_t u16x8;

static constexpr int MDIM = 16384;
static constexpr int NDIM = 4096;
static constexpr int KDIM = 4096;
static constexpr int BM = 256, BN = 256, BK = 64;
static constexpr int NT = KDIM / BK;   // 64 K-tiles, 32 iterations

__device__ __forceinline__ uint16_t f2bf(float f) {
  union { float f; uint32_t u; } c; c.f = f;
  uint32_t u = c.u;
  return (uint16_t)((u + 0x7FFFu + ((u >> 16) & 1u)) >> 16);
}

__global__ __launch_bounds__(256) void cvt_x_kernel(const float* __restrict__ x,
                                                    uint16_t* __restrict__ xb, int n8) {
  int stride = gridDim.x * blockDim.x;
  for (int t = blockIdx.x * blockDim.x + threadIdx.x; t < n8; t += stride) {
    const float4* p = reinterpret_cast<const float4*>(x + (size_t)t * 8);
    float4 a = p[0], b = p[1];
    u16x8 o;
    o[0] = f2bf(a.x); o[1] = f2bf(a.y); o[2] = f2bf(a.z); o[3] = f2bf(a.w);
    o[4] = f2bf(b.x); o[5] = f2bf(b.y); o[6] = f2bf(b.z); o[7] = f2bf(b.w);
    *reinterpret_cast<u16x8*>(xb + (size_t)t * 8) = o;
  }
}

__global__ __launch_bounds__(256) void fwht_w_kernel(const float* __restrict__ W,
                                                     uint16_t* __restrict__ Wh) {
  __shared__ float s[1024];
  const int tid = threadIdx.x;
  const size_t base = (size_t)blockIdx.x * 1024;
  reinterpret_cast<float4*>(s)[tid] = reinterpret_cast<const float4*>(W + base)[tid];
  __syncthreads();
  for (int h = 1; h < 1024; h <<= 1) {
    #pragma unroll
    for (int pp = 0; pp < 2; ++pp) {
      int p = tid + pp * 256;
      int q = p & (h - 1);
      int i = ((p - q) << 1) | q;
      float a = s[i], b = s[i + h];
      s[i] = a + b;
      s[i + h] = a - b;
    }
    __syncthreads();
  }
  #pragma unroll
  for (int pp = 0; pp < 4; ++pp) {
    int i = tid + pp * 256;
    Wh[base + i] = f2bf(s[i] * 0.03125f);
  }
}

// ---------------- 8-phase GEMM: C[M,N] = A[M,K] * B[N,K]^T ----------------
// LDS tile: 256 rows x 8 chunks(16B). chunk stored at (r,c') holds global
// chunk c = c' ^ ((r>>1)&7). Staging writes linearly; source pre-swizzled.

#define FENCE asm volatile("" ::: "memory")
#define SBAR  do { FENCE; __builtin_amdgcn_s_barrier(); \
                   __builtin_amdgcn_sched_barrier(0); } while (0)
#define LGKM0 do { asm volatile("s_waitcnt lgkmcnt(0)" ::: "memory"); \
                   __builtin_amdgcn_sched_barrier(0); } while (0)
#define VMC(n) asm volatile("s_waitcnt vmcnt(" #n ")" ::: "memory")

#define LDA4(DST, BUF, MLO, KOFF)                                              \
  do { _Pragma("unroll")                                                       \
    for (int m_ = 0; m_ < 4; ++m_)                                             \
      DST[m_] = *(const short8*)(aRd + (BUF)*32768 + ((MLO)+m_)*2048 + (KOFF)); \
  } while (0)

#define LDB4(DST, BUF, KOFF)                                                   \
  do { _Pragma("unroll")                                                       \
    for (int n_ = 0; n_ < 4; ++n_)                                             \
      DST[n_] = *(const short8*)(bRd + (BUF)*32768 + n_*2048 + (KOFF));        \
  } while (0)

#define MF16(AF, BF, MB)                                                       \
  do { __builtin_amdgcn_s_setprio(1);                                          \
    _Pragma("unroll")                                                          \
    for (int m_ = 0; m_ < 4; ++m_)                                             \
      _Pragma("unroll")                                                        \
      for (int n_ = 0; n_ < 4; ++n_)                                           \
        acc[(MB)+m_][n_] = __builtin_amdgcn_mfma_f32_16x16x32_bf16(            \
            AF[m_], BF[n_], acc[(MB)+m_][n_], 0, 0, 0);                        \
    __builtin_amdgcn_s_setprio(0);                                             \
  } while (0)

// one iteration = K-tiles T0pair=(2i in buf0, 2i+1 in buf1); stages per plan:
// ph1: t1.A.h0 | ph2: t1.A.h1 + t1.B.h1 | ph4: t2.B.h0 +VMC2 | ph5: t2.A.h0
// ph6: t2.A.h1 + t2.B.h1 | ph8: t3.B.h0 +VMC2      (t2=2i+2 buf0, t3=2i+3 buf1)
#define ITER(T1, T2, T3, FIN)                                                  \
  do {                                                                         \
    short8 aL[4], aH[4], bK[4];                                                \
    /* ph1 */ stageA(1, 0, (T1));                                              \
    LDA4(aL, 0, 0, k0off); LDB4(bK, 0, k0off);                                 \
    SBAR; LGKM0; MF16(aL, bK, 0); SBAR;                                        \
    /* ph2 */ stageA(1, 1, (T1)); stageB(1, 1, (T1));                          \
    LDA4(aH, 0, 4, k0off);                                                     \
    SBAR; LGKM0; MF16(aH, bK, 4); SBAR;                                        \
    /* ph3 */ LDA4(aL, 0, 0, k1off); LDB4(bK, 0, k1off);                       \
    SBAR; LGKM0; MF16(aL, bK, 0); SBAR;                                        \
    /* ph4 */ if (!(FIN)) stageB(0, 0, (T2));                                  \
    LDA4(aH, 0, 4, k1off);                                                     \
    if (FIN) { VMC(0); } else { VMC(2); }                                      \
    SBAR; LGKM0; MF16(aH, bK, 4); SBAR;                                        \
    /* ph5 */ if (!(FIN)) stageA(0, 0, (T2));                                  \
    LDA4(aL, 1, 0, k0off); LDB4(bK, 1, k0off);                                 \
    SBAR; LGKM0; MF16(aL, bK, 0); SBAR;                                        \
    /* ph6 */ if (!(FIN)) { stageA(0, 1, (T2)); stageB(0, 1, (T2)); }          \
    LDA4(aH, 1, 4, k0off);                                                     \
    SBAR; LGKM0; MF16(aH, bK, 4); SBAR;                                        \
    /* ph7 */ LDA4(aL, 1, 0, k1off); LDB4(bK, 1, k1off);                       \
    SBAR; LGKM0; MF16(aL, bK, 0); SBAR;                                        \
    /* ph8 */ if (!(FIN)) { stageB(1, 0, (T3)); }                              \
    LDA4(aH, 1, 4, k1off);                                                     \
    if (!(FIN)) { VMC(2); }                                                    \
    SBAR; LGKM0; MF16(aH, bK, 4); SBAR;                                        \
  } while (0)

__global__ __launch_bounds__(512, 2) void gemm_bt(const uint16_t* __restrict__ A,
                                                  const uint16_t* __restrict__ B,
                                                  float* __restrict__ C) {
  __shared__ __align__(16) uint16_t Ab[2][BM * BK];   // 2 x 32 KiB
  __shared__ __align__(16) uint16_t Bb[2][BN * BK];   // 2 x 32 KiB

  const int tid = threadIdx.x;
  const int wv  = tid >> 6;
  const int l   = tid & 63;

  // XCD-bijective swizzle (1024 wgs % 8 == 0)
  const int wg = ((blockIdx.x & 7) << 7) | (blockIdx.x >> 3);
  const int tm = wg >> 4;          // 64 M-tiles
  const int tn = wg & 15;          // 16 N-tiles
  const int wm = wv >> 2;          // 0..1 -> rows wm*128
  const int wn = wv & 3;           // 0..3 -> cols wn*64

  // ---- staging source (inverse-swizzled global), 2 x 16B per half-tile ----
  // linear chunk n = j*512 + tid -> r = j*64 + (tid>>3), c' = tid&7
  // source chunk c = c' ^ ((r>>1)&7) = (tid&7) ^ ((tid>>4)&7)
  const int t8  = tid >> 3;
  const int swz = (tid & 7) ^ ((tid >> 4) & 7);
  const uint16_t* sA = A + (size_t)(tm * BM + t8) * KDIM + swz * 8;
  const uint16_t* sB = B + (size_t)(tn * BN + t8) * KDIM + swz * 8;

  auto stageA = [&](int buf, int half, int tk) {
    #pragma unroll
    for (int j = 0; j < 2; ++j)
      __builtin_amdgcn_global_load_lds(
          (const __attribute__((address_space(1))) unsigned int*)
              (sA + (size_t)(half * 128 + j * 64) * KDIM + tk * BK),
          (__attribute__((address_space(3))) unsigned int*)
              ((char*)&Ab[buf][0] + half * 16384 + j * 8192 + wv * 1024),
          16, 0, 0);
  };
  auto stageB = [&](int buf, int half, int tk) {
    #pragma unroll
    for (int j = 0; j < 2; ++j)
      __builtin_amdgcn_global_load_lds(
          (const __attribute__((address_space(1))) unsigned int*)
              (sB + (size_t)(half * 128 + j * 64) * KDIM + tk * BK),
          (__attribute__((address_space(3))) unsigned int*)
              ((char*)&Bb[buf][0] + half * 16384 + j * 8192 + wv * 1024),
          16, 0, 0);
  };

  // ---- swizzled ds_read bases ----
  // frag row R: A = wm*128 + m*16 + lA ; B = wn*64 + n*16 + lA  (128 B rows)
  // logical chunk = ksub*4 + hi ; physical = logical ^ ((R>>1)&7), (R>>1)&7 = (lA>>1)
  const int lA = l & 15, hi = l >> 4;
  const int xr = (lA >> 1) & 7;
  const int k0off = (hi ^ xr) * 16;
  const int k1off = k0off ^ 64;            // (logical^4): +64B with XOR
  const char* aRd = (const char*)&Ab[0][0] + (wm * 128 + lA) * 128;
  const char* bRd = (const char*)&Bb[0][0] + (wn * 64 + lA) * 128;

  f32x4 acc[8][4] = {};

  // ---- prologue: t0 fully + t1.B.h0 ----
  stageA(0, 0, 0); stageA(0, 1, 0); stageB(0, 0, 0); stageB(0, 1, 0);
  stageB(1, 0, 1);
  VMC(2);            // t0's 8 loads landed; t1.B.h0 in flight
  SBAR;

  #pragma unroll 1
  for (int i = 0; i < NT / 2 - 1; ++i)     // i = 0..30
    ITER(2 * i + 1, 2 * i + 2, 2 * i + 3, 0);
  ITER(NT - 1, 0, 0, 1);                   // final: stages only t63 remainder

  // ---- epilogue: C/D layout col = lane&15, row = (lane>>4)*4 + j ----
  float* Cp = C + (size_t)(tm * BM + wm * 128) * NDIM + tn * BN + wn * 64;
  const int co = hi * 4;
  #pragma unroll
  for (int m = 0; m < 8; ++m)
    #pragma unroll
    for (int n = 0; n < 4; ++n)
      #pragma unroll
      for (int j = 0; j < 4; ++j)
        Cp[(size_t)(m * 16 + co + j) * NDIM + n * 16 + lA] = acc[m][n][j];
}

extern "C" void kernel_launch(void* const* d_in, const int* in_sizes, int n_in,
                              void* d_out, int out_size, void* d_ws, size_t ws_size,
                              hipStream_t stream) {
  (void)in_sizes; (void)n_in; (void)out_size; (void)ws_size;
  const float* x = (const float*)d_in[0];   // (4,4096,4096) f32
  const float* w = (const float*)d_in[1];   // (4096,4096) f32
  float* out = (float*)d_out;               // (4,4096,4096) f32

  uint16_t* xb = (uint16_t*)d_ws;                       // 128 MiB
  uint16_t* wh = xb + (size_t)MDIM * KDIM;              // 32 MiB

  cvt_x_kernel<<<2048, 256, 0, stream>>>(x, xb, (int)((MDIM * (size_t)KDIM) / 8));
  fwht_w_kernel<<<(NDIM * KDIM) / 1024, 256, 0, stream>>>(w, wh);
  gemm_bt<<<(MDIM / BM) * (NDIM / BN), 512, 0, stream>>>(xb, wh, out);
}

// Round 4
// 596.442 us; speedup vs baseline: 1.6715x; 1.1637x over previous
//
#include <hip/hip_runtime.h>
#include <hip/hip_bf16.h>
#include <stdint.h>

// HadLinear: out = blockFWHT1024(x)/32 @ W^T  ==  x @ (blockFWHT1024(W rows)/32)^T
// (1) x f32->bf16, (2) Wh = FWHT(W)/32 -> bf16, (3) bf16 MFMA GEMM.
// GEMM: 8-phase schedule, BM=BN=256, BK=64, 8 waves (2Mx4N), 2-buffer LDS.
// R4: single barrier per phase (stage/read disjointness verified), VMC moved
// post-MFMA (bigger landing window), reads issued before stages per phase.

typedef __attribute__((ext_vector_type(8))) short    short8;
typedef __attribute__((ext_vector_type(4))) float    f32x4;
typedef __attribute__((ext_vector_type(8))) uint16_t u16x8;

static constexpr int MDIM = 16384;
static constexpr int NDIM = 4096;
static constexpr int KDIM = 4096;
static constexpr int BM = 256, BN = 256, BK = 64;
static constexpr int NT = KDIM / BK;   // 64 K-tiles, 32 iterations

__device__ __forceinline__ uint16_t f2bf(float f) {
  union { float f; uint32_t u; } c; c.f = f;
  uint32_t u = c.u;
  return (uint16_t)((u + 0x7FFFu + ((u >> 16) & 1u)) >> 16);
}

__global__ __launch_bounds__(256) void cvt_x_kernel(const float* __restrict__ x,
                                                    uint16_t* __restrict__ xb, int n8) {
  int stride = gridDim.x * blockDim.x;
  for (int t = blockIdx.x * blockDim.x + threadIdx.x; t < n8; t += stride) {
    const float4* p = reinterpret_cast<const float4*>(x + (size_t)t * 8);
    float4 a = p[0], b = p[1];
    u16x8 o;
    o[0] = f2bf(a.x); o[1] = f2bf(a.y); o[2] = f2bf(a.z); o[3] = f2bf(a.w);
    o[4] = f2bf(b.x); o[5] = f2bf(b.y); o[6] = f2bf(b.z); o[7] = f2bf(b.w);
    *reinterpret_cast<u16x8*>(xb + (size_t)t * 8) = o;
  }
}

__global__ __launch_bounds__(256) void fwht_w_kernel(const float* __restrict__ W,
                                                     uint16_t* __restrict__ Wh) {
  __shared__ float s[1024];
  const int tid = threadIdx.x;
  const size_t base = (size_t)blockIdx.x * 1024;
  reinterpret_cast<float4*>(s)[tid] = reinterpret_cast<const float4*>(W + base)[tid];
  __syncthreads();
  for (int h = 1; h < 1024; h <<= 1) {
    #pragma unroll
    for (int pp = 0; pp < 2; ++pp) {
      int p = tid + pp * 256;
      int q = p & (h - 1);
      int i = ((p - q) << 1) | q;
      float a = s[i], b = s[i + h];
      s[i] = a + b;
      s[i + h] = a - b;
    }
    __syncthreads();
  }
  #pragma unroll
  for (int pp = 0; pp < 4; ++pp) {
    int i = tid + pp * 256;
    Wh[base + i] = f2bf(s[i] * 0.03125f);
  }
}

// ---------------- 8-phase GEMM: C[M,N] = A[M,K] * B[N,K]^T ----------------
// LDS tile: 256 rows x 8 chunks(16B). chunk stored at (r,c') holds global
// chunk c = c' ^ ((r>>1)&7). Staging writes linearly; source pre-swizzled.

#define FENCE asm volatile("" ::: "memory")
#define SBAR  do { FENCE; __builtin_amdgcn_s_barrier(); \
                   __builtin_amdgcn_sched_barrier(0); } while (0)
#define LGKM0 do { asm volatile("s_waitcnt lgkmcnt(0)" ::: "memory"); \
                   __builtin_amdgcn_sched_barrier(0); } while (0)
#define VMC(n) do { asm volatile("s_waitcnt vmcnt(" #n ")" ::: "memory"); \
                    __builtin_amdgcn_sched_barrier(0); } while (0)

#define LDA4(DST, BUF, MLO, KOFF)                                              \
  do { _Pragma("unroll")                                                       \
    for (int m_ = 0; m_ < 4; ++m_)                                             \
      DST[m_] = *(const short8*)(aRd + (BUF)*32768 + ((MLO)+m_)*2048 + (KOFF)); \
  } while (0)

#define LDB4(DST, BUF, KOFF)                                                   \
  do { _Pragma("unroll")                                                       \
    for (int n_ = 0; n_ < 4; ++n_)                                             \
      DST[n_] = *(const short8*)(bRd + (BUF)*32768 + n_*2048 + (KOFF));        \
  } while (0)

#define MF16(AF, BF, MB)                                                       \
  do { __builtin_amdgcn_s_setprio(1);                                          \
    _Pragma("unroll")                                                          \
    for (int m_ = 0; m_ < 4; ++m_)                                             \
      _Pragma("unroll")                                                        \
      for (int n_ = 0; n_ < 4; ++n_)                                           \
        acc[(MB)+m_][n_] = __builtin_amdgcn_mfma_f32_16x16x32_bf16(            \
            AF[m_], BF[n_], acc[(MB)+m_][n_], 0, 0, 0);                        \
    __builtin_amdgcn_s_setprio(0);                                             \
  } while (0)

// Iteration i consumes tiles 2i (buf0, ph1-4) and T1=2i+1 (buf1, ph5-8).
// Stages: ph1 T1.A.h0 | ph2 T1.A.h1+B.h1 | ph4 T2.B.h0 | ph5 T2.A.h0
//         ph6 T2.A.h1+B.h1 | ph8 T3.B.h0   (T2=2i+2 buf0, T3=2i+3 buf1)
// VMC(2) post-MFMA at ph4 (T1 landed) and ph8 (T2 landed).
// Single SBAR per phase: stage(p) disjoint from read(p); stage(p) vs read(p-1)
// closed by barrier semantics (reads complete before wave reaches SBAR(p)).
#define ITER(T1, T2, T3, FIN)                                                  \
  do {                                                                         \
    short8 aL[4], aH[4], bK[4];                                                \
    /* ph1 */ SBAR;                                                            \
    LDB4(bK, 0, k0off); LDA4(aL, 0, 0, k0off);                                 \
    stageA(1, 0, (T1));                                                        \
    LGKM0; MF16(aL, bK, 0);                                                    \
    /* ph2 */ SBAR;                                                            \
    LDA4(aH, 0, 4, k0off);                                                     \
    stageA(1, 1, (T1)); stageB(1, 1, (T1));                                    \
    LGKM0; MF16(aH, bK, 4);                                                    \
    /* ph3 */ SBAR;                                                            \
    LDB4(bK, 0, k1off); LDA4(aL, 0, 0, k1off);                                 \
    LGKM0; MF16(aL, bK, 0);                                                    \
    /* ph4 */ SBAR;                                                            \
    LDA4(aH, 0, 4, k1off);                                                     \
    if (!(FIN)) stageB(0, 0, (T2));                                            \
    LGKM0; MF16(aH, bK, 4);                                                    \
    if (FIN) { VMC(0); } else { VMC(2); }                                      \
    /* ph5 */ SBAR;                                                            \
    LDB4(bK, 1, k0off); LDA4(aL, 1, 0, k0off);                                 \
    if (!(FIN)) stageA(0, 0, (T2));                                            \
    LGKM0; MF16(aL, bK, 0);                                                    \
    /* ph6 */ SBAR;                                                            \
    LDA4(aH, 1, 4, k0off);                                                     \
    if (!(FIN)) { stageA(0, 1, (T2)); stageB(0, 1, (T2)); }                    \
    LGKM0; MF16(aH, bK, 4);                                                    \
    /* ph7 */ SBAR;                                                            \
    LDB4(bK, 1, k1off); LDA4(aL, 1, 0, k1off);                                 \
    LGKM0; MF16(aL, bK, 0);                                                    \
    /* ph8 */ SBAR;                                                            \
    LDA4(aH, 1, 4, k1off);                                                     \
    if (!(FIN)) stageB(1, 0, (T3));                                            \
    LGKM0; MF16(aH, bK, 4);                                                    \
    if (!(FIN)) { VMC(2); }                                                    \
  } while (0)

__global__ __launch_bounds__(512, 2) void gemm_bt(const uint16_t* __restrict__ A,
                                                  const uint16_t* __restrict__ B,
                                                  float* __restrict__ C) {
  __shared__ __align__(16) uint16_t Ab[2][BM * BK];   // 2 x 32 KiB
  __shared__ __align__(16) uint16_t Bb[2][BN * BK];   // 2 x 32 KiB

  const int tid = threadIdx.x;
  const int wv  = tid >> 6;
  const int l   = tid & 63;

  // XCD-bijective swizzle (1024 wgs % 8 == 0)
  const int wg = ((blockIdx.x & 7) << 7) | (blockIdx.x >> 3);
  const int tm = wg >> 4;          // 64 M-tiles
  const int tn = wg & 15;          // 16 N-tiles
  const int wm = wv >> 2;          // 0..1 -> rows wm*128
  const int wn = wv & 3;           // 0..3 -> cols wn*64

  // ---- staging source (inverse-swizzled global) ----
  // linear chunk n = j*512 + tid -> r = j*64 + (tid>>3), c' = tid&7
  // source chunk c = c' ^ ((r>>1)&7) = (tid&7) ^ ((tid>>4)&7)
  const int t8  = tid >> 3;
  const int swz = (tid & 7) ^ ((tid >> 4) & 7);
  const uint16_t* sA = A + (size_t)(tm * BM + t8) * KDIM + swz * 8;
  const uint16_t* sB = B + (size_t)(tn * BN + t8) * KDIM + swz * 8;

  auto stageA = [&](int buf, int half, int tk) {
    #pragma unroll
    for (int j = 0; j < 2; ++j)
      __builtin_amdgcn_global_load_lds(
          (const __attribute__((address_space(1))) unsigned int*)
              (sA + (size_t)(half * 128 + j * 64) * KDIM + tk * BK),
          (__attribute__((address_space(3))) unsigned int*)
              ((char*)&Ab[buf][0] + half * 16384 + j * 8192 + wv * 1024),
          16, 0, 0);
  };
  auto stageB = [&](int buf, int half, int tk) {
    #pragma unroll
    for (int j = 0; j < 2; ++j)
      __builtin_amdgcn_global_load_lds(
          (const __attribute__((address_space(1))) unsigned int*)
              (sB + (size_t)(half * 128 + j * 64) * KDIM + tk * BK),
          (__attribute__((address_space(3))) unsigned int*)
              ((char*)&Bb[buf][0] + half * 16384 + j * 8192 + wv * 1024),
          16, 0, 0);
  };

  // ---- swizzled ds_read bases ----
  const int lA = l & 15, hi = l >> 4;
  const int xr = (lA >> 1) & 7;
  const int k0off = (hi ^ xr) * 16;
  const int k1off = k0off ^ 64;
  const char* aRd = (const char*)&Ab[0][0] + (wm * 128 + lA) * 128;
  const char* bRd = (const char*)&Bb[0][0] + (wn * 64 + lA) * 128;

  f32x4 acc[8][4] = {};

  // ---- prologue: t0 fully + t1.B.h0 ----
  stageA(0, 0, 0); stageA(0, 1, 0); stageB(0, 0, 0); stageB(0, 1, 0);
  stageB(1, 0, 1);
  VMC(2);            // t0's 8 loads landed; t1.B.h0 in flight

  #pragma unroll 1
  for (int i = 0; i < NT / 2 - 1; ++i)     // i = 0..30
    ITER(2 * i + 1, 2 * i + 2, 2 * i + 3, 0);
  ITER(NT - 1, 0, 0, 1);                   // final iteration

  // ---- epilogue: C/D layout col = lane&15, row = (lane>>4)*4 + j ----
  float* Cp = C + (size_t)(tm * BM + wm * 128) * NDIM + tn * BN + wn * 64;
  const int co = hi * 4;
  #pragma unroll
  for (int m = 0; m < 8; ++m)
    #pragma unroll
    for (int n = 0; n < 4; ++n)
      #pragma unroll
      for (int j = 0; j < 4; ++j)
        Cp[(size_t)(m * 16 + co + j) * NDIM + n * 16 + lA] = acc[m][n][j];
}

extern "C" void kernel_launch(void* const* d_in, const int* in_sizes, int n_in,
                              void* d_out, int out_size, void* d_ws, size_t ws_size,
                              hipStream_t stream) {
  (void)in_sizes; (void)n_in; (void)out_size; (void)ws_size;
  const float* x = (const float*)d_in[0];   // (4,4096,4096) f32
  const float* w = (const float*)d_in[1];   // (4096,4096) f32
  float* out = (float*)d_out;               // (4,4096,4096) f32

  uint16_t* xb = (uint16_t*)d_ws;                       // 128 MiB
  uint16_t* wh = xb + (size_t)MDIM * KDIM;              // 32 MiB

  cvt_x_kernel<<<2048, 256, 0, stream>>>(x, xb, (int)((MDIM * (size_t)KDIM) / 8));
  fwht_w_kernel<<<(NDIM * KDIM) / 1024, 256, 0, stream>>>(w, wh);
  gemm_bt<<<(MDIM / BM) * (NDIM / BN), 512, 0, stream>>>(xb, wh, out);
}